// Round 19
// baseline (308.343 us; speedup 1.0000x reference)
//
#include <hip/hip_runtime.h>
#include <math.h>

typedef unsigned short u16;
typedef unsigned int   u32;
typedef __attribute__((ext_vector_type(8))) _Float16 half8;
typedef __attribute__((ext_vector_type(4))) float    f32x4;

#define PI_F 3.14159265358979323846f

__device__ __forceinline__ float lrelu_f(float x){ return x >= 0.f ? x : 0.05f*x; }
__device__ __forceinline__ u16 f2h(float f){ _Float16 h = (_Float16)f; u16 u; __builtin_memcpy(&u,&h,2); return u; }
__device__ __forceinline__ float h2f(u16 u){ _Float16 h; __builtin_memcpy(&h,&u,2); return (float)h; }

// ---------------------------------------------------------------------------
// Consolidated one-time prep (R17-verified; dispatched by blockIdx.y).
//  map: xu RASTER order (flat = oh*(Wo*9)+ow*9+kh*3+kw, C-order reshape — R9
//  lesson: never decode blockwise).  Weights: NHWC-k chunked [co][ch][KCm],
//  k-within-chunk = tl*CIP+ci; pad cols/channels/taps zero -> inert in MFMA.
//  pwh columns permuted to NHWC-flat: k_nhwc = pos*128+co <-> k_ref = co*20+pos.
// ---------------------------------------------------------------------------
struct PrepP {
    int *map0, *map1;
    const float *sc0_w, *sc1_w;
    u16 *wb0, *wb1;
    const float *c2_w, *c3_w, *c4_w, *c5_w;
    u16 *wb2, *wb3, *wb4, *wb5;
    const float *pw, *wih, *whh;
    u16 *pwh, *wihh, *whhh;
};

__device__ void d_map(int* map, int H, int W, int Wo, int total, int i)
{
    if (i >= total) return;
    int oh  = i / (Wo*9);
    int rem = i % (Wo*9);
    int ow  = rem / 9;
    int r2  = rem % 9;
    int kh  = r2/3, kw = r2%3;
    int ihc = min(oh*2, H-1);
    int lat = min(max(ihc + kh - 1, 0), H-1);
    float phi = ((float)lat + 0.5f)/(float)H * PI_F - 0.5f*PI_F;
    float ca  = fmaxf(fabsf(cosf(phi)), 1e-3f);
    float d   = fminf(0.8f/ca, 4.0f);
    float jw  = (float)((ow*2) % W);
    float lonf = rintf(jw + d*(float)(kw-1));   // np.round == rint (half-even)
    int lon = (int)lonf % W; if (lon < 0) lon += W;
    map[i] = lat*W + lon;
}

__device__ void d_wsph(const float* w3, u16* wh, int CO, int CI, int CIP,
                       int TPC, int NCH, int KCd, int KCm, int total, int i)
{
    if (i >= total) return;
    int j = i % KCm, t = i / KCm;
    int ch = t % NCH, co = t / NCH;
    float s = 0.f;
    if (j < KCd){
        int tl = j / CIP, ci = j % CIP;
        int tap = ch*TPC + tl;
        if (ci < CI && tap < 25){
            int u = tap/5, v = tap%5;
            const float* w = w3 + (co*CI + ci)*9;
            int pl0 = max(0, u-2), pl1 = min(2, u);
            int q0 = max(0, v-2), q1 = min(2, v);
            for (int pl=pl0; pl<=pl1; ++pl)
                for (int q=q0; q<=q1; ++q) s += w[pl*3+q];
            s *= (1.0f/9.0f);
        }
    }
    wh[i] = f2h(s);
}

__device__ void d_wdir(const float* w, u16* wh, int CO, int CI, int TPC,
                       int NCH, int KPQ, int KCm, int total, int i)
{
    if (i >= total) return;
    int j = i % KCm, t = i / KCm;
    int ch = t % NCH, co = t / NCH;
    int tl = j / CI, ci = j % CI;
    int tap = ch*TPC + tl;
    wh[i] = f2h(w[(size_t)(co*CI + ci)*KPQ + tap]);
}

__global__ void k_prep(PrepP p)
{
    int i = blockIdx.x*blockDim.x + threadIdx.x;
    switch (blockIdx.y){
    case 0:  d_map(p.map0, 64, 128, 64, 18432, i); break;
    case 1:  d_map(p.map1, 31,  63, 32,  4608, i); break;
    case 2:  d_wsph(p.sc0_w, p.wb0, 32,  6,  8, 13, 2, 104, 128,  8192, i); break;
    case 3:  d_wsph(p.sc1_w, p.wb1, 64, 32, 32,  5, 5, 160, 160, 51200, i); break;
    case 4:  d_wdir(p.c2_w, p.wb2,  64,  64, 3, 3, 9, 192,  36864, i); break;
    case 5:  d_wdir(p.c3_w, p.wb3,  64,  64, 2, 2, 4, 128,  16384, i); break;
    case 6:  d_wdir(p.c4_w, p.wb4, 128,  64, 3, 3, 9, 192,  73728, i); break;
    case 7:  d_wdir(p.c5_w, p.wb5, 128, 128, 1, 9, 9, 128, 147456, i); break;
    case 8:  if (i < 256*2560){
                 int n = i / 2560, k = i % 2560;
                 int pos = k >> 7, co = k & 127;
                 p.pwh[i] = f2h(p.pw[(size_t)n*2560 + co*20 + pos]);
             } break;
    case 9:  if (i < 768*256) p.wihh[i] = f2h(p.wih[i]); break;
    default: if (i < 768*256) p.whhh[i] = f2h(p.whh[i]); break;
    }
}

// ---------------------------------------------------------------------------
// xu0: NCHW fp32 x -> NHWC u16 [b][pos(96x192)][8] (ch 6,7 zero-padded).
// (xu1 is not materialized — folded into L1's stage A, R17/R19.)
// ---------------------------------------------------------------------------
__global__ void k_xu0(const float* __restrict__ x, const int* __restrict__ map,
                      u16* __restrict__ out)
{
    int p = blockIdx.x*blockDim.x + threadIdx.x;   // 0..18431
    int b = blockIdx.y;
    int m = map[p];
    const float* xb = x + (size_t)b*6*8192 + m;
    u16 v[8];
    #pragma unroll
    for (int c=0;c<6;++c) v[c] = f2h(xb[c*8192]);
    v[6]=0; v[7]=0;
    *reinterpret_cast<uint4*>(out + ((size_t)b*18432 + p)*8) =
        *reinterpret_cast<uint4*>(v);
}

// ---------------------------------------------------------------------------
// NHWC MFMA conv engine, 2-D wave tiling (R16/R17-verified). GATHER path
// (R19): the 18 KB raster map is cached in LDS at block start — R18's
// pos -> global-map -> gather dependent chain was the L1 regression
// (62->78 µs); ds_read breaks it while keeping the traffic win (FETCH
// 48->26 MB). Values bit-identical.
// Fragment layout (guide §3, m89-verified): A/B lane&15 = M/N, k=(lane>>4)*8+j;
// D col=lane&15 (-> co), row=(lane>>4)*4+reg (-> n).
// ---------------------------------------------------------------------------
template<int CO,int OW,int NTOT,int NB,int IH,int IW,int KW,int S,int CI,
         int TPC,int NCH,int KCm,int KCp,int WR,int WC,int WN,int WM,
         int GATHER=0,int INTOT=0,int MAPSZ=1>
__global__ __launch_bounds__(256) void k_nconv(
    const u16* __restrict__ in, const int* __restrict__ map,
    const u16* __restrict__ wh,
    const float* __restrict__ bg, const float* __restrict__ bb,
    const float* __restrict__ bm, const float* __restrict__ bv,
    u16* __restrict__ out)
{
    constexpr int NT_N = WR*WN;
    constexpr int NPAD = NT_N*16;
    constexpr int KCd  = TPC*CI;
    constexpr int CIV  = CI/8;
    static_assert(WR*WC == 4, "4 waves");
    static_assert(WC*WM*16 == CO, "co tiling covers CO");
    static_assert(CI % 8 == 0, "16B staging vectors");
    static_assert(KCm % 32 == 0 && KCp % 8 == 0 && KCd <= KCm, "tiling");
    static_assert((NPAD & (NPAD-1)) == 0, "NPAD pow2");
    static_assert(!GATHER || MAPSZ >= IH*IW, "LDS map covers raster");
    __shared__ __align__(16) u16 sA[NPAD*KCp];
    __shared__ __align__(16) u16 sB[CO*KCp];
    __shared__ int smap[MAPSZ];

    int b  = blockIdx.x / NB;
    int n0 = (blockIdx.x % NB)*NPAD;
    int tid = threadIdx.x;
    const u16* xb = in + (GATHER ? (size_t)b*INTOT*CI : (size_t)b*IH*IW*CI);

    if constexpr (GATHER){
        for (int i = tid; i < MAPSZ; i += 256) smap[i] = map[i];
    }
    if constexpr (KCm > KCd){
        constexpr int PADW = KCm - KCd;
        for (int e = tid; e < NPAD*PADW; e += 256)
            sA[(e/PADW)*KCp + KCd + e%PADW] = 0;
    }
    if constexpr (GATHER) __syncthreads();   // smap visible before stage A

    int w = tid >> 6, lane = tid & 63, l15 = lane & 15, l4 = lane >> 4;
    int wr = w / WC, wc = w % WC;
    f32x4 acc[WN][WM];
    #pragma unroll
    for (int i=0;i<WN;++i)
        #pragma unroll
        for (int j=0;j<WM;++j) acc[i][j] = (f32x4){0.f,0.f,0.f,0.f};

    for (int ch = 0; ch < NCH; ++ch){
        if (ch) __syncthreads();
        // stage A: per (n, tap, ch-vec8) one 16B copy; tap row is contiguous
        constexpr int ITER = NPAD*TPC*CIV;
        for (int i = tid; i < ITER; i += 256){
            int n_l = i / (TPC*CIV);
            int r   = i - n_l*(TPC*CIV);
            int tl  = r / CIV;
            int civ = r - tl*CIV;
            int n_g = min(n0 + n_l, NTOT-1);
            int oh = n_g/OW, ow = n_g - oh*OW;
            int tap = ch*TPC + tl;
            int u = tap/KW, v = tap - u*KW;
            int pos = (oh*S + u)*IW + ow*S + v;
            const u16* src;
            if constexpr (GATHER){
                int m = smap[pos];                   // LDS-resident raster map
                src = xb + (size_t)m*CI + civ*8;
            } else {
                src = xb + (size_t)pos*CI + civ*8;
            }
            uint4 val = *reinterpret_cast<const uint4*>(src);
            *reinterpret_cast<uint4*>(&sA[n_l*KCp + tl*CI + civ*8]) = val;
        }
        // stage B: weights (16B copies)
        constexpr int W8 = KCm/8;
        for (int i = tid; i < CO*W8; i += 256){
            int co = i / W8, j = (i - co*W8)*8;
            uint4 v = *reinterpret_cast<const uint4*>(wh + ((size_t)co*NCH + ch)*KCm + j);
            *reinterpret_cast<uint4*>(&sB[co*KCp + j]) = v;
        }
        __syncthreads();
        // MFMA: wave (wr,wc) computes WN x WM tiles; (WN+WM) reads per step
        #pragma unroll
        for (int ks = 0; ks < KCm/32; ++ks){
            half8 a[WN], bf[WM];
            #pragma unroll
            for (int i=0;i<WN;++i)
                a[i] = *reinterpret_cast<const half8*>(
                    &sA[((wr*WN+i)*16 + l15)*KCp + ks*32 + l4*8]);
            #pragma unroll
            for (int j=0;j<WM;++j)
                bf[j] = *reinterpret_cast<const half8*>(
                    &sB[((wc*WM+j)*16 + l15)*KCp + ks*32 + l4*8]);
            #pragma unroll
            for (int i=0;i<WN;++i)
                #pragma unroll
                for (int j=0;j<WM;++j)
                    acc[i][j] = __builtin_amdgcn_mfma_f32_16x16x32_f16(a[i], bf[j], acc[i][j], 0, 0, 0);
        }
    }
    // epilogue: BN + lrelu, NHWC [b][n][co] (lanes -> consecutive co: coalesced)
    #pragma unroll
    for (int j=0;j<WM;++j){
        int co = (wc*WM+j)*16 + l15;
        float inv = bg[co]*rsqrtf(bv[co]+1e-5f);
        float shv = bb[co] - bm[co]*inv;
        #pragma unroll
        for (int i=0;i<WN;++i){
            #pragma unroll
            for (int r=0;r<4;++r){
                int gn = n0 + (wr*WN+i)*16 + l4*4 + r;
                if (gn < NTOT)
                    out[((size_t)b*NTOT + gn)*CO + co] = f2h(lrelu_f(fmaf(acc[i][j][r], inv, shv)));
            }
        }
    }
}

// ---------------------------------------------------------------------------
// Head GEMM: fused = lrelu(h5flat[256x2560] @ pwh^T + v@vproj^T + vproj_b).
// 64x64 tiles, grid(4,4). Output f16. (R15-verified.)
// ---------------------------------------------------------------------------
__global__ __launch_bounds__(256) void k_head2(
    const u16* __restrict__ h5, const u16* __restrict__ pwh,
    const float* __restrict__ vin, const float* __restrict__ vproj_w,
    const float* __restrict__ vproj_b, u16* __restrict__ fusedh)
{
    __shared__ __align__(16) u16 sA[64*136];
    __shared__ __align__(16) u16 sB[64*136];
    __shared__ float sv[64*9];
    int m0 = blockIdx.x*64, nc0 = blockIdx.y*64;
    int tid = threadIdx.x;
    int w = tid >> 6, lane = tid & 63, l15 = lane & 15, l4 = lane >> 4;
    f32x4 acc[4];
    #pragma unroll
    for (int j=0;j<4;++j) acc[j] = (f32x4){0.f,0.f,0.f,0.f};

    for (int i = tid; i < 576; i += 256) sv[i] = vin[(m0 + i/9)*9 + i%9];

    for (int kc0 = 0; kc0 < 2560; kc0 += 128){
        if (kc0) __syncthreads();
        for (int i = tid; i < 1024; i += 256){
            int r = i >> 4, jv = (i & 15)*8;
            *reinterpret_cast<uint4*>(&sA[r*136 + jv]) =
                *reinterpret_cast<const uint4*>(h5 + (size_t)(m0+r)*2560 + kc0 + jv);
            *reinterpret_cast<uint4*>(&sB[r*136 + jv]) =
                *reinterpret_cast<const uint4*>(pwh + (size_t)(nc0+r)*2560 + kc0 + jv);
        }
        __syncthreads();
        #pragma unroll
        for (int ks = 0; ks < 4; ++ks){
            half8 a = *reinterpret_cast<const half8*>(&sA[(w*16 + l15)*136 + ks*32 + l4*8]);
            #pragma unroll
            for (int j=0;j<4;++j){
                half8 bf = *reinterpret_cast<const half8*>(&sB[(j*16 + l15)*136 + ks*32 + l4*8]);
                acc[j] = __builtin_amdgcn_mfma_f32_16x16x32_f16(a, bf, acc[j], 0, 0, 0);
            }
        }
    }
    #pragma unroll
    for (int j=0;j<4;++j){
        int nc = nc0 + j*16 + l15;
        float bias = vproj_b[nc];
        #pragma unroll
        for (int r=0;r<4;++r){
            int ml = w*16 + l4*4 + r;
            float av = 0.f;
            #pragma unroll
            for (int k=0;k<9;++k) av = fmaf(sv[ml*9+k], vproj_w[nc*9+k], av);
            fusedh[(size_t)(m0+ml)*256 + nc] = f2h(lrelu_f(acc[j][r] + av + bias));
        }
    }
}

// ---------------------------------------------------------------------------
// GRU gate GEMM: gbuf[:,0:768] = fused @ wih^T ; gbuf[:,768:1536] = hx @ whh^T.
// grid(4, 24): y = half*12 + ntile. (R15-verified.)
// ---------------------------------------------------------------------------
__global__ __launch_bounds__(256) void k_ggemm(
    const u16* __restrict__ fusedh, const float* __restrict__ hx,
    const u16* __restrict__ wihh, const u16* __restrict__ whhh,
    float* __restrict__ gbuf)
{
    __shared__ __align__(16) u16 sA[64*136];
    __shared__ __align__(16) u16 sB[64*136];
    int m0 = blockIdx.x*64;
    int t  = blockIdx.y;
    int half = t / 12, nt = t - half*12;
    int n0 = nt*64;
    const u16* B = (half ? whhh : wihh) + (size_t)n0*256;
    int tid = threadIdx.x;
    int w = tid >> 6, lane = tid & 63, l15 = lane & 15, l4 = lane >> 4;
    f32x4 acc[4];
    #pragma unroll
    for (int j=0;j<4;++j) acc[j] = (f32x4){0.f,0.f,0.f,0.f};

    for (int kc0 = 0; kc0 < 256; kc0 += 128){
        if (kc0) __syncthreads();
        for (int i = tid; i < 1024; i += 256){
            int r = i >> 4, jv = (i & 15)*8;
            if (half == 0){
                *reinterpret_cast<uint4*>(&sA[r*136 + jv]) =
                    *reinterpret_cast<const uint4*>(fusedh + (size_t)(m0+r)*256 + kc0 + jv);
            } else {
                const float* src = hx + (size_t)(m0+r)*256 + kc0 + jv;
                float4 f0 = *reinterpret_cast<const float4*>(src);
                float4 f1 = *reinterpret_cast<const float4*>(src+4);
                u16 v[8] = { f2h(f0.x),f2h(f0.y),f2h(f0.z),f2h(f0.w),
                             f2h(f1.x),f2h(f1.y),f2h(f1.z),f2h(f1.w) };
                *reinterpret_cast<uint4*>(&sA[r*136 + jv]) = *reinterpret_cast<uint4*>(v);
            }
            *reinterpret_cast<uint4*>(&sB[r*136 + jv]) =
                *reinterpret_cast<const uint4*>(B + (size_t)r*256 + kc0 + jv);
        }
        __syncthreads();
        #pragma unroll
        for (int ks = 0; ks < 4; ++ks){
            half8 a = *reinterpret_cast<const half8*>(&sA[(w*16 + l15)*136 + ks*32 + l4*8]);
            #pragma unroll
            for (int j=0;j<4;++j){
                half8 bf = *reinterpret_cast<const half8*>(&sB[(j*16 + l15)*136 + ks*32 + l4*8]);
                acc[j] = __builtin_amdgcn_mfma_f32_16x16x32_f16(a, bf, acc[j], 0, 0, 0);
            }
        }
    }
    #pragma unroll
    for (int j=0;j<4;++j){
        int nc = half*768 + n0 + j*16 + l15;
        #pragma unroll
        for (int r=0;r<4;++r){
            int m = m0 + w*16 + l4*4 + r;
            gbuf[(size_t)m*1536 + nc] = acc[j][r];
        }
    }
}

// ---------------------------------------------------------------------------
// Fused GRU gate + act head (R17-verified).
// ---------------------------------------------------------------------------
__global__ __launch_bounds__(256) void k_gate_act(
    const float* __restrict__ gbuf, const float* __restrict__ hx,
    const float* __restrict__ bih, const float* __restrict__ bhh,
    const float* __restrict__ fc_w,
    float* __restrict__ hx_new, float* __restrict__ act)
{
    __shared__ float sh[256];
    int b = blockIdx.x, j = threadIdx.x;
    const float* g = gbuf + (size_t)b*1536;
    float ir = g[j]       + bih[j];
    float iz = g[256+j]   + bih[256+j];
    float in_= g[512+j]   + bih[512+j];
    float hr = g[768+j]   + bhh[j];
    float hz = g[1024+j]  + bhh[256+j];
    float hn = g[1280+j]  + bhh[512+j];
    float r = 1.f/(1.f+expf(-(ir+hr)));
    float z = 1.f/(1.f+expf(-(iz+hz)));
    float n = tanhf(in_ + r*hn);
    float h = (1.f-z)*n + z*hx[b*256+j];
    hx_new[b*256+j] = h;
    sh[j] = lrelu_f(h);
    __syncthreads();
    int w = j >> 6, lane = j & 63;
    const float* fw = fc_w + w*256;
    int k0 = lane*4;
    float a = sh[k0]*fw[k0] + sh[k0+1]*fw[k0+1] + sh[k0+2]*fw[k0+2] + sh[k0+3]*fw[k0+3];
    #pragma unroll
    for (int off = 32; off; off >>= 1) a += __shfl_down(a, off);
    if (lane == 0) act[b*4 + w] = a;
}

extern "C" void kernel_launch(void* const* d_in, const int* in_sizes, int n_in,
                              void* d_out, int out_size, void* d_ws, size_t ws_size,
                              hipStream_t stream)
{
    const float* x      = (const float*)d_in[0];
    const float* vin    = (const float*)d_in[1];
    const float* hx     = (const float*)d_in[2];
    const float* sc0_w  = (const float*)d_in[3];
    const float* bn0g   = (const float*)d_in[4];
    const float* bn0b   = (const float*)d_in[5];
    const float* bn0m   = (const float*)d_in[6];
    const float* bn0v   = (const float*)d_in[7];
    const float* sc1_w  = (const float*)d_in[8];
    const float* bn1g   = (const float*)d_in[9];
    const float* bn1b   = (const float*)d_in[10];
    const float* bn1m   = (const float*)d_in[11];
    const float* bn1v   = (const float*)d_in[12];
    const float* c2_w   = (const float*)d_in[13];
    const float* bn2g   = (const float*)d_in[14];
    const float* bn2b   = (const float*)d_in[15];
    const float* bn2m   = (const float*)d_in[16];
    const float* bn2v   = (const float*)d_in[17];
    const float* c3_w   = (const float*)d_in[18];
    const float* bn3g   = (const float*)d_in[19];
    const float* bn3b   = (const float*)d_in[20];
    const float* bn3m   = (const float*)d_in[21];
    const float* bn3v   = (const float*)d_in[22];
    const float* c4_w   = (const float*)d_in[23];
    const float* bn4g   = (const float*)d_in[24];
    const float* bn4b   = (const float*)d_in[25];
    const float* bn4m   = (const float*)d_in[26];
    const float* bn4v   = (const float*)d_in[27];
    const float* c5_w   = (const float*)d_in[28];
    const float* bn5g   = (const float*)d_in[29];
    const float* bn5b   = (const float*)d_in[30];
    const float* bn5m   = (const float*)d_in[31];
    const float* bn5v   = (const float*)d_in[32];
    const float* proj_w = (const float*)d_in[33];
    const float* vproj_w= (const float*)d_in[34];
    const float* vproj_b= (const float*)d_in[35];
    const float* gru_wih= (const float*)d_in[36];
    const float* gru_whh= (const float*)d_in[37];
    const float* gru_bih= (const float*)d_in[38];
    const float* gru_bhh= (const float*)d_in[39];
    const float* fc_w   = (const float*)d_in[40];

    char* base = (char*)d_ws;
    size_t off = 0;
    auto alloc = [&](size_t bytes)->char*{
        char* p = base + off; off += (bytes + 255) & ~(size_t)255; return p;
    };
    int* map0 = (int*)alloc((size_t)96*192*4);
    int* map1 = (int*)alloc((size_t)48*96*4);
    u16* wb0  = (u16*)alloc((size_t)32*2*128*2);
    u16* wb1  = (u16*)alloc((size_t)64*5*160*2);
    u16* wb2  = (u16*)alloc((size_t)64*3*192*2);
    u16* wb3  = (u16*)alloc((size_t)64*2*128*2);
    u16* wb4  = (u16*)alloc((size_t)128*3*192*2);
    u16* wb5  = (u16*)alloc((size_t)128*9*128*2);
    u16* pwh  = (u16*)alloc((size_t)256*2560*2);
    u16* wihh = (u16*)alloc((size_t)768*256*2);
    u16* whhh = (u16*)alloc((size_t)768*256*2);
    u16* xu   = (u16*)alloc((size_t)256*18432*8*2);   // xu0 only (xu1 folded)
    u16* h0   = (u16*)alloc((size_t)256*1953*32*2);
    u16* h1   = (u16*)alloc((size_t)256*465*64*2);
    u16* h2   = (u16*)alloc((size_t)256*377*64*2);
    u16* h3   = (u16*)alloc((size_t)256*84*64*2);
    u16* h4   = (u16*)alloc((size_t)256*48*128*2);
    u16* h5   = (u16*)alloc((size_t)256*20*128*2);
    u16* fusedh = (u16*)alloc((size_t)256*256*2);
    float* gbuf = (float*)alloc((size_t)256*1536*4);

    // ---- one-time prep (single launch, y-dispatched) ----
    PrepP pp = { map0, map1, sc0_w, sc1_w, wb0, wb1,
                 c2_w, c3_w, c4_w, c5_w, wb2, wb3, wb4, wb5,
                 proj_w, gru_wih, gru_whh, pwh, wihh, whhh };
    k_prep<<<dim3(2560, 11), 256, 0, stream>>>(pp);

    // ---- backbone (NHWC, MFMA f16, 2-D wave tiles) ----
    // k_nconv<CO,OW,NTOT,NB,IH,IW,KW,S,CI,TPC,NCH,KCm,KCp,WR,WC,WN,WM[,GATHER,INTOT,MAPSZ]>
    k_xu0<<<dim3(72, 256), 256, 0, stream>>>(x, map0, xu);
    k_nconv<32,63,1953,16, 96,192, 5,3, 8,13,2, 128,136, 4,1,2,2>
        <<<256*16, 256, 0, stream>>>(xu, nullptr, wb0, bn0g,bn0b,bn0m,bn0v, h0);
    k_nconv<64,31,465,8, 48,96, 5,3, 32,5,5, 160,168, 2,2,2,2, 1,1953,4608>
        <<<256*8, 256, 0, stream>>>(h0, map1, wb1, bn1g,bn1b,bn1m,bn1v, h1);
    k_nconv<64,29,377,6, 15,31, 3,1, 64,3,3, 192,200, 2,2,2,2>
        <<<256*6, 256, 0, stream>>>(h1, nullptr, wb2, bn2g,bn2b,bn2m,bn2v, h2);
    k_nconv<64,14,84,3, 13,29, 2,2, 64,2,2, 128,136, 2,2,1,2>
        <<<256*3, 256, 0, stream>>>(h2, nullptr, wb3, bn3g,bn3b,bn3m,bn3v, h3);
    k_nconv<128,12,48,3, 6,14, 3,1, 64,3,3, 192,200, 1,4,1,2>
        <<<256*3, 256, 0, stream>>>(h3, nullptr, wb4, bn4g,bn4b,bn4m,bn4v, h4);
    k_nconv<128,10,20,2, 4,12, 3,1, 128,1,9, 128,136, 1,4,1,2>
        <<<256*2, 256, 0, stream>>>(h4, nullptr, wb5, bn5g,bn5b,bn5m,bn5v, h5);

    // ---- head (MFMA GEMMs) ----
    k_head2<<<dim3(4,4), 256, 0, stream>>>(h5, pwh, vin, vproj_w, vproj_b, fusedh);
    k_ggemm<<<dim3(4,24), 256, 0, stream>>>(fusedh, hx, wihh, whhh, gbuf);
    float* outp = (float*)d_out;
    k_gate_act<<<256, 256, 0, stream>>>(gbuf, hx, gru_bih, gru_bhh, fc_w,
                                        outp + 1024, outp);
}

// Round 20
// 295.934 us; speedup vs baseline: 1.0419x; 1.0419x over previous
//
#include <hip/hip_runtime.h>
#include <math.h>

typedef unsigned short u16;
typedef unsigned int   u32;
typedef __attribute__((ext_vector_type(8))) _Float16 half8;
typedef __attribute__((ext_vector_type(4))) float    f32x4;

#define PI_F 3.14159265358979323846f

__device__ __forceinline__ float lrelu_f(float x){ return x >= 0.f ? x : 0.05f*x; }
__device__ __forceinline__ u16 f2h(float f){ _Float16 h = (_Float16)f; u16 u; __builtin_memcpy(&u,&h,2); return u; }
__device__ __forceinline__ float h2f(u16 u){ _Float16 h; __builtin_memcpy(&h,&u,2); return (float)h; }

// ---------------------------------------------------------------------------
// Consolidated one-time prep (R17-verified; dispatched by blockIdx.y).
//  map: xu RASTER order (flat = oh*(Wo*9)+ow*9+kh*3+kw, C-order reshape — R9
//  lesson: never decode blockwise).  map1 stored as u16 (values < 1953) so
//  the conv kernel's LDS copy costs 9 KB not 18 KB (R19 lesson: the int smap
//  dropped 3->2 blocks/CU).  Weights: NHWC-k chunked [co][ch][KCm],
//  k-within-chunk = tl*CIP+ci; pad cols/channels/taps zero -> inert in MFMA.
//  pwh columns permuted to NHWC-flat: k_nhwc = pos*128+co <-> k_ref = co*20+pos.
// ---------------------------------------------------------------------------
struct PrepP {
    int *map0; u16 *map1h;
    const float *sc0_w, *sc1_w;
    u16 *wb0, *wb1;
    const float *c2_w, *c3_w, *c4_w, *c5_w;
    u16 *wb2, *wb3, *wb4, *wb5;
    const float *pw, *wih, *whh;
    u16 *pwh, *wihh, *whhh;
};

template<typename T>
__device__ void d_map(T* map, int H, int W, int Wo, int total, int i)
{
    if (i >= total) return;
    int oh  = i / (Wo*9);
    int rem = i % (Wo*9);
    int ow  = rem / 9;
    int r2  = rem % 9;
    int kh  = r2/3, kw = r2%3;
    int ihc = min(oh*2, H-1);
    int lat = min(max(ihc + kh - 1, 0), H-1);
    float phi = ((float)lat + 0.5f)/(float)H * PI_F - 0.5f*PI_F;
    float ca  = fmaxf(fabsf(cosf(phi)), 1e-3f);
    float d   = fminf(0.8f/ca, 4.0f);
    float jw  = (float)((ow*2) % W);
    float lonf = rintf(jw + d*(float)(kw-1));   // np.round == rint (half-even)
    int lon = (int)lonf % W; if (lon < 0) lon += W;
    map[i] = (T)(lat*W + lon);
}

__device__ void d_wsph(const float* w3, u16* wh, int CO, int CI, int CIP,
                       int TPC, int NCH, int KCd, int KCm, int total, int i)
{
    if (i >= total) return;
    int j = i % KCm, t = i / KCm;
    int ch = t % NCH, co = t / NCH;
    float s = 0.f;
    if (j < KCd){
        int tl = j / CIP, ci = j % CIP;
        int tap = ch*TPC + tl;
        if (ci < CI && tap < 25){
            int u = tap/5, v = tap%5;
            const float* w = w3 + (co*CI + ci)*9;
            int pl0 = max(0, u-2), pl1 = min(2, u);
            int q0 = max(0, v-2), q1 = min(2, v);
            for (int pl=pl0; pl<=pl1; ++pl)
                for (int q=q0; q<=q1; ++q) s += w[pl*3+q];
            s *= (1.0f/9.0f);
        }
    }
    wh[i] = f2h(s);
}

__device__ void d_wdir(const float* w, u16* wh, int CO, int CI, int TPC,
                       int NCH, int KPQ, int KCm, int total, int i)
{
    if (i >= total) return;
    int j = i % KCm, t = i / KCm;
    int ch = t % NCH, co = t / NCH;
    int tl = j / CI, ci = j % CI;
    int tap = ch*TPC + tl;
    wh[i] = f2h(w[(size_t)(co*CI + ci)*KPQ + tap]);
}

__global__ void k_prep(PrepP p)
{
    int i = blockIdx.x*blockDim.x + threadIdx.x;
    switch (blockIdx.y){
    case 0:  d_map<int>(p.map0, 64, 128, 64, 18432, i); break;
    case 1:  d_map<u16>(p.map1h, 31, 63, 32, 4608, i); break;
    case 2:  d_wsph(p.sc0_w, p.wb0, 32,  6,  8, 13, 2, 104, 128,  8192, i); break;
    case 3:  d_wsph(p.sc1_w, p.wb1, 64, 32, 32,  5, 5, 160, 160, 51200, i); break;
    case 4:  d_wdir(p.c2_w, p.wb2,  64,  64, 3, 3, 9, 192,  36864, i); break;
    case 5:  d_wdir(p.c3_w, p.wb3,  64,  64, 2, 2, 4, 128,  16384, i); break;
    case 6:  d_wdir(p.c4_w, p.wb4, 128,  64, 3, 3, 9, 192,  73728, i); break;
    case 7:  d_wdir(p.c5_w, p.wb5, 128, 128, 1, 9, 9, 128, 147456, i); break;
    case 8:  if (i < 256*2560){
                 int n = i / 2560, k = i % 2560;
                 int pos = k >> 7, co = k & 127;
                 p.pwh[i] = f2h(p.pw[(size_t)n*2560 + co*20 + pos]);
             } break;
    case 9:  if (i < 768*256) p.wihh[i] = f2h(p.wih[i]); break;
    default: if (i < 768*256) p.whhh[i] = f2h(p.whh[i]); break;
    }
}

// ---------------------------------------------------------------------------
// xu0: NCHW fp32 x -> NHWC u16 [b][pos(96x192)][8] (ch 6,7 zero-padded).
// (xu1 is not materialized — folded into L1's stage A, R17/R20.)
// ---------------------------------------------------------------------------
__global__ void k_xu0(const float* __restrict__ x, const int* __restrict__ map,
                      u16* __restrict__ out)
{
    int p = blockIdx.x*blockDim.x + threadIdx.x;   // 0..18431
    int b = blockIdx.y;
    int m = map[p];
    const float* xb = x + (size_t)b*6*8192 + m;
    u16 v[8];
    #pragma unroll
    for (int c=0;c<6;++c) v[c] = f2h(xb[c*8192]);
    v[6]=0; v[7]=0;
    *reinterpret_cast<uint4*>(out + ((size_t)b*18432 + p)*8) =
        *reinterpret_cast<uint4*>(v);
}

// ---------------------------------------------------------------------------
// NHWC MFMA conv engine, 2-D wave tiling (R16/R17-verified). GATHER path
// (R20): the raster map is cached in LDS as u16 (9 KB) — breaks R18's
// pos -> global-map -> gather dependent chain (62->78 µs regression)
// WITHOUT R19's occupancy loss (int smap = 18 KB dropped 3->2 blocks/CU).
// Values bit-identical.
// Fragment layout (guide §3, m89-verified): A/B lane&15 = M/N, k=(lane>>4)*8+j;
// D col=lane&15 (-> co), row=(lane>>4)*4+reg (-> n).
// ---------------------------------------------------------------------------
template<int CO,int OW,int NTOT,int NB,int IH,int IW,int KW,int S,int CI,
         int TPC,int NCH,int KCm,int KCp,int WR,int WC,int WN,int WM,
         int GATHER=0,int INTOT=0,int MAPSZ=1>
__global__ __launch_bounds__(256) void k_nconv(
    const u16* __restrict__ in, const u16* __restrict__ map,
    const u16* __restrict__ wh,
    const float* __restrict__ bg, const float* __restrict__ bb,
    const float* __restrict__ bm, const float* __restrict__ bv,
    u16* __restrict__ out)
{
    constexpr int NT_N = WR*WN;
    constexpr int NPAD = NT_N*16;
    constexpr int KCd  = TPC*CI;
    constexpr int CIV  = CI/8;
    static_assert(WR*WC == 4, "4 waves");
    static_assert(WC*WM*16 == CO, "co tiling covers CO");
    static_assert(CI % 8 == 0, "16B staging vectors");
    static_assert(KCm % 32 == 0 && KCp % 8 == 0 && KCd <= KCm, "tiling");
    static_assert((NPAD & (NPAD-1)) == 0, "NPAD pow2");
    static_assert(!GATHER || MAPSZ >= IH*IW, "LDS map covers raster");
    __shared__ __align__(16) u16 sA[NPAD*KCp];
    __shared__ __align__(16) u16 sB[CO*KCp];
    __shared__ u16 smap[GATHER ? MAPSZ : 2];

    int b  = blockIdx.x / NB;
    int n0 = (blockIdx.x % NB)*NPAD;
    int tid = threadIdx.x;
    const u16* xb = in + (GATHER ? (size_t)b*INTOT*CI : (size_t)b*IH*IW*CI);

    if constexpr (GATHER){
        for (int i = tid; i < MAPSZ; i += 256) smap[i] = map[i];
    }
    if constexpr (KCm > KCd){
        constexpr int PADW = KCm - KCd;
        for (int e = tid; e < NPAD*PADW; e += 256)
            sA[(e/PADW)*KCp + KCd + e%PADW] = 0;
    }
    if constexpr (GATHER) __syncthreads();   // smap visible before stage A

    int w = tid >> 6, lane = tid & 63, l15 = lane & 15, l4 = lane >> 4;
    int wr = w / WC, wc = w % WC;
    f32x4 acc[WN][WM];
    #pragma unroll
    for (int i=0;i<WN;++i)
        #pragma unroll
        for (int j=0;j<WM;++j) acc[i][j] = (f32x4){0.f,0.f,0.f,0.f};

    for (int ch = 0; ch < NCH; ++ch){
        if (ch) __syncthreads();
        // stage A: per (n, tap, ch-vec8) one 16B copy; tap row is contiguous
        constexpr int ITER = NPAD*TPC*CIV;
        for (int i = tid; i < ITER; i += 256){
            int n_l = i / (TPC*CIV);
            int r   = i - n_l*(TPC*CIV);
            int tl  = r / CIV;
            int civ = r - tl*CIV;
            int n_g = min(n0 + n_l, NTOT-1);
            int oh = n_g/OW, ow = n_g - oh*OW;
            int tap = ch*TPC + tl;
            int u = tap/KW, v = tap - u*KW;
            int pos = (oh*S + u)*IW + ow*S + v;
            const u16* src;
            if constexpr (GATHER){
                int m = (int)smap[pos];              // LDS-resident u16 map
                src = xb + (size_t)m*CI + civ*8;
            } else {
                src = xb + (size_t)pos*CI + civ*8;
            }
            uint4 val = *reinterpret_cast<const uint4*>(src);
            *reinterpret_cast<uint4*>(&sA[n_l*KCp + tl*CI + civ*8]) = val;
        }
        // stage B: weights (16B copies)
        constexpr int W8 = KCm/8;
        for (int i = tid; i < CO*W8; i += 256){
            int co = i / W8, j = (i - co*W8)*8;
            uint4 v = *reinterpret_cast<const uint4*>(wh + ((size_t)co*NCH + ch)*KCm + j);
            *reinterpret_cast<uint4*>(&sB[co*KCp + j]) = v;
        }
        __syncthreads();
        // MFMA: wave (wr,wc) computes WN x WM tiles; (WN+WM) reads per step
        #pragma unroll
        for (int ks = 0; ks < KCm/32; ++ks){
            half8 a[WN], bf[WM];
            #pragma unroll
            for (int i=0;i<WN;++i)
                a[i] = *reinterpret_cast<const half8*>(
                    &sA[((wr*WN+i)*16 + l15)*KCp + ks*32 + l4*8]);
            #pragma unroll
            for (int j=0;j<WM;++j)
                bf[j] = *reinterpret_cast<const half8*>(
                    &sB[((wc*WM+j)*16 + l15)*KCp + ks*32 + l4*8]);
            #pragma unroll
            for (int i=0;i<WN;++i)
                #pragma unroll
                for (int j=0;j<WM;++j)
                    acc[i][j] = __builtin_amdgcn_mfma_f32_16x16x32_f16(a[i], bf[j], acc[i][j], 0, 0, 0);
        }
    }
    // epilogue: BN + lrelu, NHWC [b][n][co] (lanes -> consecutive co: coalesced)
    #pragma unroll
    for (int j=0;j<WM;++j){
        int co = (wc*WM+j)*16 + l15;
        float inv = bg[co]*rsqrtf(bv[co]+1e-5f);
        float shv = bb[co] - bm[co]*inv;
        #pragma unroll
        for (int i=0;i<WN;++i){
            #pragma unroll
            for (int r=0;r<4;++r){
                int gn = n0 + (wr*WN+i)*16 + l4*4 + r;
                if (gn < NTOT)
                    out[((size_t)b*NTOT + gn)*CO + co] = f2h(lrelu_f(fmaf(acc[i][j][r], inv, shv)));
            }
        }
    }
}

// ---------------------------------------------------------------------------
// Head GEMM: fused = lrelu(h5flat[256x2560] @ pwh^T + v@vproj^T + vproj_b).
// 64x64 tiles, grid(4,4). Output f16. (R15-verified.)
// ---------------------------------------------------------------------------
__global__ __launch_bounds__(256) void k_head2(
    const u16* __restrict__ h5, const u16* __restrict__ pwh,
    const float* __restrict__ vin, const float* __restrict__ vproj_w,
    const float* __restrict__ vproj_b, u16* __restrict__ fusedh)
{
    __shared__ __align__(16) u16 sA[64*136];
    __shared__ __align__(16) u16 sB[64*136];
    __shared__ float sv[64*9];
    int m0 = blockIdx.x*64, nc0 = blockIdx.y*64;
    int tid = threadIdx.x;
    int w = tid >> 6, lane = tid & 63, l15 = lane & 15, l4 = lane >> 4;
    f32x4 acc[4];
    #pragma unroll
    for (int j=0;j<4;++j) acc[j] = (f32x4){0.f,0.f,0.f,0.f};

    for (int i = tid; i < 576; i += 256) sv[i] = vin[(m0 + i/9)*9 + i%9];

    for (int kc0 = 0; kc0 < 2560; kc0 += 128){
        if (kc0) __syncthreads();
        for (int i = tid; i < 1024; i += 256){
            int r = i >> 4, jv = (i & 15)*8;
            *reinterpret_cast<uint4*>(&sA[r*136 + jv]) =
                *reinterpret_cast<const uint4*>(h5 + (size_t)(m0+r)*2560 + kc0 + jv);
            *reinterpret_cast<uint4*>(&sB[r*136 + jv]) =
                *reinterpret_cast<const uint4*>(pwh + (size_t)(nc0+r)*2560 + kc0 + jv);
        }
        __syncthreads();
        #pragma unroll
        for (int ks = 0; ks < 4; ++ks){
            half8 a = *reinterpret_cast<const half8*>(&sA[(w*16 + l15)*136 + ks*32 + l4*8]);
            #pragma unroll
            for (int j=0;j<4;++j){
                half8 bf = *reinterpret_cast<const half8*>(&sB[(j*16 + l15)*136 + ks*32 + l4*8]);
                acc[j] = __builtin_amdgcn_mfma_f32_16x16x32_f16(a, bf, acc[j], 0, 0, 0);
            }
        }
    }
    #pragma unroll
    for (int j=0;j<4;++j){
        int nc = nc0 + j*16 + l15;
        float bias = vproj_b[nc];
        #pragma unroll
        for (int r=0;r<4;++r){
            int ml = w*16 + l4*4 + r;
            float av = 0.f;
            #pragma unroll
            for (int k=0;k<9;++k) av = fmaf(sv[ml*9+k], vproj_w[nc*9+k], av);
            fusedh[(size_t)(m0+ml)*256 + nc] = f2h(lrelu_f(acc[j][r] + av + bias));
        }
    }
}

// ---------------------------------------------------------------------------
// GRU gate GEMM: gbuf[:,0:768] = fused @ wih^T ; gbuf[:,768:1536] = hx @ whh^T.
// grid(4, 24): y = half*12 + ntile. (R15-verified.)
// ---------------------------------------------------------------------------
__global__ __launch_bounds__(256) void k_ggemm(
    const u16* __restrict__ fusedh, const float* __restrict__ hx,
    const u16* __restrict__ wihh, const u16* __restrict__ whhh,
    float* __restrict__ gbuf)
{
    __shared__ __align__(16) u16 sA[64*136];
    __shared__ __align__(16) u16 sB[64*136];
    int m0 = blockIdx.x*64;
    int t  = blockIdx.y;
    int half = t / 12, nt = t - half*12;
    int n0 = nt*64;
    const u16* B = (half ? whhh : wihh) + (size_t)n0*256;
    int tid = threadIdx.x;
    int w = tid >> 6, lane = tid & 63, l15 = lane & 15, l4 = lane >> 4;
    f32x4 acc[4];
    #pragma unroll
    for (int j=0;j<4;++j) acc[j] = (f32x4){0.f,0.f,0.f,0.f};

    for (int kc0 = 0; kc0 < 256; kc0 += 128){
        if (kc0) __syncthreads();
        for (int i = tid; i < 1024; i += 256){
            int r = i >> 4, jv = (i & 15)*8;
            if (half == 0){
                *reinterpret_cast<uint4*>(&sA[r*136 + jv]) =
                    *reinterpret_cast<const uint4*>(fusedh + (size_t)(m0+r)*256 + kc0 + jv);
            } else {
                const float* src = hx + (size_t)(m0+r)*256 + kc0 + jv;
                float4 f0 = *reinterpret_cast<const float4*>(src);
                float4 f1 = *reinterpret_cast<const float4*>(src+4);
                u16 v[8] = { f2h(f0.x),f2h(f0.y),f2h(f0.z),f2h(f0.w),
                             f2h(f1.x),f2h(f1.y),f2h(f1.z),f2h(f1.w) };
                *reinterpret_cast<uint4*>(&sA[r*136 + jv]) = *reinterpret_cast<uint4*>(v);
            }
            *reinterpret_cast<uint4*>(&sB[r*136 + jv]) =
                *reinterpret_cast<const uint4*>(B + (size_t)r*256 + kc0 + jv);
        }
        __syncthreads();
        #pragma unroll
        for (int ks = 0; ks < 4; ++ks){
            half8 a = *reinterpret_cast<const half8*>(&sA[(w*16 + l15)*136 + ks*32 + l4*8]);
            #pragma unroll
            for (int j=0;j<4;++j){
                half8 bf = *reinterpret_cast<const half8*>(&sB[(j*16 + l15)*136 + ks*32 + l4*8]);
                acc[j] = __builtin_amdgcn_mfma_f32_16x16x32_f16(a, bf, acc[j], 0, 0, 0);
            }
        }
    }
    #pragma unroll
    for (int j=0;j<4;++j){
        int nc = half*768 + n0 + j*16 + l15;
        #pragma unroll
        for (int r=0;r<4;++r){
            int m = m0 + w*16 + l4*4 + r;
            gbuf[(size_t)m*1536 + nc] = acc[j][r];
        }
    }
}

// ---------------------------------------------------------------------------
// Fused GRU gate + act head (R17-verified).
// ---------------------------------------------------------------------------
__global__ __launch_bounds__(256) void k_gate_act(
    const float* __restrict__ gbuf, const float* __restrict__ hx,
    const float* __restrict__ bih, const float* __restrict__ bhh,
    const float* __restrict__ fc_w,
    float* __restrict__ hx_new, float* __restrict__ act)
{
    __shared__ float sh[256];
    int b = blockIdx.x, j = threadIdx.x;
    const float* g = gbuf + (size_t)b*1536;
    float ir = g[j]       + bih[j];
    float iz = g[256+j]   + bih[256+j];
    float in_= g[512+j]   + bih[512+j];
    float hr = g[768+j]   + bhh[j];
    float hz = g[1024+j]  + bhh[256+j];
    float hn = g[1280+j]  + bhh[512+j];
    float r = 1.f/(1.f+expf(-(ir+hr)));
    float z = 1.f/(1.f+expf(-(iz+hz)));
    float n = tanhf(in_ + r*hn);
    float h = (1.f-z)*n + z*hx[b*256+j];
    hx_new[b*256+j] = h;
    sh[j] = lrelu_f(h);
    __syncthreads();
    int w = j >> 6, lane = j & 63;
    const float* fw = fc_w + w*256;
    int k0 = lane*4;
    float a = sh[k0]*fw[k0] + sh[k0+1]*fw[k0+1] + sh[k0+2]*fw[k0+2] + sh[k0+3]*fw[k0+3];
    #pragma unroll
    for (int off = 32; off; off >>= 1) a += __shfl_down(a, off);
    if (lane == 0) act[b*4 + w] = a;
}

extern "C" void kernel_launch(void* const* d_in, const int* in_sizes, int n_in,
                              void* d_out, int out_size, void* d_ws, size_t ws_size,
                              hipStream_t stream)
{
    const float* x      = (const float*)d_in[0];
    const float* vin    = (const float*)d_in[1];
    const float* hx     = (const float*)d_in[2];
    const float* sc0_w  = (const float*)d_in[3];
    const float* bn0g   = (const float*)d_in[4];
    const float* bn0b   = (const float*)d_in[5];
    const float* bn0m   = (const float*)d_in[6];
    const float* bn0v   = (const float*)d_in[7];
    const float* sc1_w  = (const float*)d_in[8];
    const float* bn1g   = (const float*)d_in[9];
    const float* bn1b   = (const float*)d_in[10];
    const float* bn1m   = (const float*)d_in[11];
    const float* bn1v   = (const float*)d_in[12];
    const float* c2_w   = (const float*)d_in[13];
    const float* bn2g   = (const float*)d_in[14];
    const float* bn2b   = (const float*)d_in[15];
    const float* bn2m   = (const float*)d_in[16];
    const float* bn2v   = (const float*)d_in[17];
    const float* c3_w   = (const float*)d_in[18];
    const float* bn3g   = (const float*)d_in[19];
    const float* bn3b   = (const float*)d_in[20];
    const float* bn3m   = (const float*)d_in[21];
    const float* bn3v   = (const float*)d_in[22];
    const float* c4_w   = (const float*)d_in[23];
    const float* bn4g   = (const float*)d_in[24];
    const float* bn4b   = (const float*)d_in[25];
    const float* bn4m   = (const float*)d_in[26];
    const float* bn4v   = (const float*)d_in[27];
    const float* c5_w   = (const float*)d_in[28];
    const float* bn5g   = (const float*)d_in[29];
    const float* bn5b   = (const float*)d_in[30];
    const float* bn5m   = (const float*)d_in[31];
    const float* bn5v   = (const float*)d_in[32];
    const float* proj_w = (const float*)d_in[33];
    const float* vproj_w= (const float*)d_in[34];
    const float* vproj_b= (const float*)d_in[35];
    const float* gru_wih= (const float*)d_in[36];
    const float* gru_whh= (const float*)d_in[37];
    const float* gru_bih= (const float*)d_in[38];
    const float* gru_bhh= (const float*)d_in[39];
    const float* fc_w   = (const float*)d_in[40];

    char* base = (char*)d_ws;
    size_t off = 0;
    auto alloc = [&](size_t bytes)->char*{
        char* p = base + off; off += (bytes + 255) & ~(size_t)255; return p;
    };
    int* map0 = (int*)alloc((size_t)96*192*4);
    u16* map1h= (u16*)alloc((size_t)48*96*2);
    u16* wb0  = (u16*)alloc((size_t)32*2*128*2);
    u16* wb1  = (u16*)alloc((size_t)64*5*160*2);
    u16* wb2  = (u16*)alloc((size_t)64*3*192*2);
    u16* wb3  = (u16*)alloc((size_t)64*2*128*2);
    u16* wb4  = (u16*)alloc((size_t)128*3*192*2);
    u16* wb5  = (u16*)alloc((size_t)128*9*128*2);
    u16* pwh  = (u16*)alloc((size_t)256*2560*2);
    u16* wihh = (u16*)alloc((size_t)768*256*2);
    u16* whhh = (u16*)alloc((size_t)768*256*2);
    u16* xu   = (u16*)alloc((size_t)256*18432*8*2);   // xu0 only (xu1 folded)
    u16* h0   = (u16*)alloc((size_t)256*1953*32*2);
    u16* h1   = (u16*)alloc((size_t)256*465*64*2);
    u16* h2   = (u16*)alloc((size_t)256*377*64*2);
    u16* h3   = (u16*)alloc((size_t)256*84*64*2);
    u16* h4   = (u16*)alloc((size_t)256*48*128*2);
    u16* h5   = (u16*)alloc((size_t)256*20*128*2);
    u16* fusedh = (u16*)alloc((size_t)256*256*2);
    float* gbuf = (float*)alloc((size_t)256*1536*4);

    // ---- one-time prep (single launch, y-dispatched) ----
    PrepP pp = { map0, map1h, sc0_w, sc1_w, wb0, wb1,
                 c2_w, c3_w, c4_w, c5_w, wb2, wb3, wb4, wb5,
                 proj_w, gru_wih, gru_whh, pwh, wihh, whhh };
    k_prep<<<dim3(2560, 11), 256, 0, stream>>>(pp);

    // ---- backbone (NHWC, MFMA f16, 2-D wave tiles) ----
    // k_nconv<CO,OW,NTOT,NB,IH,IW,KW,S,CI,TPC,NCH,KCm,KCp,WR,WC,WN,WM[,GATHER,INTOT,MAPSZ]>
    k_xu0<<<dim3(72, 256), 256, 0, stream>>>(x, map0, xu);
    k_nconv<32,63,1953,16, 96,192, 5,3, 8,13,2, 128,136, 4,1,2,2>
        <<<256*16, 256, 0, stream>>>(xu, nullptr, wb0, bn0g,bn0b,bn0m,bn0v, h0);
    k_nconv<64,31,465,8, 48,96, 5,3, 32,5,5, 160,168, 2,2,2,2, 1,1953,4608>
        <<<256*8, 256, 0, stream>>>(h0, map1h, wb1, bn1g,bn1b,bn1m,bn1v, h1);
    k_nconv<64,29,377,6, 15,31, 3,1, 64,3,3, 192,200, 2,2,2,2>
        <<<256*6, 256, 0, stream>>>(h1, nullptr, wb2, bn2g,bn2b,bn2m,bn2v, h2);
    k_nconv<64,14,84,3, 13,29, 2,2, 64,2,2, 128,136, 2,2,1,2>
        <<<256*3, 256, 0, stream>>>(h2, nullptr, wb3, bn3g,bn3b,bn3m,bn3v, h3);
    k_nconv<128,12,48,3, 6,14, 3,1, 64,3,3, 192,200, 1,4,1,2>
        <<<256*3, 256, 0, stream>>>(h3, nullptr, wb4, bn4g,bn4b,bn4m,bn4v, h4);
    k_nconv<128,10,20,2, 4,12, 3,1, 128,1,9, 128,136, 1,4,1,2>
        <<<256*2, 256, 0, stream>>>(h4, nullptr, wb5, bn5g,bn5b,bn5m,bn5v, h5);

    // ---- head (MFMA GEMMs) ----
    k_head2<<<dim3(4,4), 256, 0, stream>>>(h5, pwh, vin, vproj_w, vproj_b, fusedh);
    k_ggemm<<<dim3(4,24), 256, 0, stream>>>(fusedh, hx, wihh, whhh, gbuf);
    float* outp = (float*)d_out;
    k_gate_act<<<256, 256, 0, stream>>>(gbuf, hx, gru_bih, gru_bhh, fc_w,
                                        outp + 1024, outp);
}

// Round 21
// 258.620 us; speedup vs baseline: 1.1923x; 1.1443x over previous
//
#include <hip/hip_runtime.h>
#include <math.h>

typedef unsigned short u16;
typedef unsigned int   u32;
typedef __attribute__((ext_vector_type(8))) _Float16 half8;
typedef __attribute__((ext_vector_type(4))) float    f32x4;

#define PI_F 3.14159265358979323846f

__device__ __forceinline__ float lrelu_f(float x){ return x >= 0.f ? x : 0.05f*x; }
__device__ __forceinline__ u16 f2h(float f){ _Float16 h = (_Float16)f; u16 u; __builtin_memcpy(&u,&h,2); return u; }
__device__ __forceinline__ float h2f(u16 u){ _Float16 h; __builtin_memcpy(&h,&u,2); return (float)h; }

// ---------------------------------------------------------------------------
// Consolidated one-time prep (R17-verified; dispatched by blockIdx.y).
// map1 stored u16 (values < 1953): 9 KB LDS copy (R19/R20 lesson).
// ---------------------------------------------------------------------------
struct PrepP {
    int *map0; u16 *map1h;
    const float *sc0_w, *sc1_w;
    u16 *wb0, *wb1;
    const float *c2_w, *c3_w, *c4_w, *c5_w;
    u16 *wb2, *wb3, *wb4, *wb5;
    const float *pw, *wih, *whh;
    u16 *pwh, *wihh, *whhh;
};

template<typename T>
__device__ void d_map(T* map, int H, int W, int Wo, int total, int i)
{
    if (i >= total) return;
    int oh  = i / (Wo*9);
    int rem = i % (Wo*9);
    int ow  = rem / 9;
    int r2  = rem % 9;
    int kh  = r2/3, kw = r2%3;
    int ihc = min(oh*2, H-1);
    int lat = min(max(ihc + kh - 1, 0), H-1);
    float phi = ((float)lat + 0.5f)/(float)H * PI_F - 0.5f*PI_F;
    float ca  = fmaxf(fabsf(cosf(phi)), 1e-3f);
    float d   = fminf(0.8f/ca, 4.0f);
    float jw  = (float)((ow*2) % W);
    float lonf = rintf(jw + d*(float)(kw-1));   // np.round == rint (half-even)
    int lon = (int)lonf % W; if (lon < 0) lon += W;
    map[i] = (T)(lat*W + lon);
}

__device__ void d_wsph(const float* w3, u16* wh, int CO, int CI, int CIP,
                       int TPC, int NCH, int KCd, int KCm, int total, int i)
{
    if (i >= total) return;
    int j = i % KCm, t = i / KCm;
    int ch = t % NCH, co = t / NCH;
    float s = 0.f;
    if (j < KCd){
        int tl = j / CIP, ci = j % CIP;
        int tap = ch*TPC + tl;
        if (ci < CI && tap < 25){
            int u = tap/5, v = tap%5;
            const float* w = w3 + (co*CI + ci)*9;
            int pl0 = max(0, u-2), pl1 = min(2, u);
            int q0 = max(0, v-2), q1 = min(2, v);
            for (int pl=pl0; pl<=pl1; ++pl)
                for (int q=q0; q<=q1; ++q) s += w[pl*3+q];
            s *= (1.0f/9.0f);
        }
    }
    wh[i] = f2h(s);
}

__device__ void d_wdir(const float* w, u16* wh, int CO, int CI, int TPC,
                       int NCH, int KPQ, int KCm, int total, int i)
{
    if (i >= total) return;
    int j = i % KCm, t = i / KCm;
    int ch = t % NCH, co = t / NCH;
    int tl = j / CI, ci = j % CI;
    int tap = ch*TPC + tl;
    wh[i] = f2h(w[(size_t)(co*CI + ci)*KPQ + tap]);
}

__global__ void k_prep(PrepP p)
{
    int i = blockIdx.x*blockDim.x + threadIdx.x;
    switch (blockIdx.y){
    case 0:  d_map<int>(p.map0, 64, 128, 64, 18432, i); break;
    case 1:  d_map<u16>(p.map1h, 31, 63, 32, 4608, i); break;
    case 2:  d_wsph(p.sc0_w, p.wb0, 32,  6,  8, 13, 2, 104, 128,  8192, i); break;
    case 3:  d_wsph(p.sc1_w, p.wb1, 64, 32, 32,  5, 5, 160, 160, 51200, i); break;
    case 4:  d_wdir(p.c2_w, p.wb2,  64,  64, 3, 3, 9, 192,  36864, i); break;
    case 5:  d_wdir(p.c3_w, p.wb3,  64,  64, 2, 2, 4, 128,  16384, i); break;
    case 6:  d_wdir(p.c4_w, p.wb4, 128,  64, 3, 3, 9, 192,  73728, i); break;
    case 7:  d_wdir(p.c5_w, p.wb5, 128, 128, 1, 9, 9, 128, 147456, i); break;
    case 8:  if (i < 256*2560){
                 int n = i / 2560, k = i % 2560;
                 int pos = k >> 7, co = k & 127;
                 p.pwh[i] = f2h(p.pw[(size_t)n*2560 + co*20 + pos]);
             } break;
    case 9:  if (i < 768*256) p.wihh[i] = f2h(p.wih[i]); break;
    default: if (i < 768*256) p.whhh[i] = f2h(p.whh[i]); break;
    }
}

// ---------------------------------------------------------------------------
// xu0: NCHW fp32 x -> NHWC u16 [b][pos(96x192)][8] (ch 6,7 zero-padded).
// ---------------------------------------------------------------------------
__global__ void k_xu0(const float* __restrict__ x, const int* __restrict__ map,
                      u16* __restrict__ out)
{
    int p = blockIdx.x*blockDim.x + threadIdx.x;   // 0..18431
    int b = blockIdx.y;
    int m = map[p];
    const float* xb = x + (size_t)b*6*8192 + m;
    u16 v[8];
    #pragma unroll
    for (int c=0;c<6;++c) v[c] = f2h(xb[c*8192]);
    v[6]=0; v[7]=0;
    *reinterpret_cast<uint4*>(out + ((size_t)b*18432 + p)*8) =
        *reinterpret_cast<uint4*>(v);
}

// ---------------------------------------------------------------------------
// NHWC MFMA conv engine, 2-D wave tiling (R16-R20 verified). R21: BT template
// — 512-thread (8-wave) blocks for the big layers. LDS (52-78 KB) caps
// residency at 2-3 blocks/CU regardless of block size, so doubling waves per
// block raises resident waves/CU 12 -> 16-24 (the L1 gather chain was
// latency-bound at 26% occupancy). Tile geometry (1.0 frag-reads/MFMA at
// WN=WM=2) preserved via WR*WC = BT/64.
// GATHER path: u16 raster map cached in LDS (9 KB) — breaks the
// pos -> map -> gather chain without R19's occupancy loss.
// Fragment layout (guide §3, m89-verified): A/B lane&15 = M/N, k=(lane>>4)*8+j;
// D col=lane&15 (-> co), row=(lane>>4)*4+reg (-> n).
// ---------------------------------------------------------------------------
template<int BT,int CO,int OW,int NTOT,int NB,int IH,int IW,int KW,int S,int CI,
         int TPC,int NCH,int KCm,int KCp,int WR,int WC,int WN,int WM,
         int GATHER=0,int INTOT=0,int MAPSZ=1>
__global__ __launch_bounds__(BT) void k_nconv(
    const u16* __restrict__ in, const u16* __restrict__ map,
    const u16* __restrict__ wh,
    const float* __restrict__ bg, const float* __restrict__ bb,
    const float* __restrict__ bm, const float* __restrict__ bv,
    u16* __restrict__ out)
{
    constexpr int NT_N = WR*WN;
    constexpr int NPAD = NT_N*16;
    constexpr int KCd  = TPC*CI;
    constexpr int CIV  = CI/8;
    static_assert(WR*WC == BT/64, "waves cover block");
    static_assert(WC*WM*16 == CO, "co tiling covers CO");
    static_assert(CI % 8 == 0, "16B staging vectors");
    static_assert(KCm % 32 == 0 && KCp % 8 == 0 && KCd <= KCm, "tiling");
    static_assert((NPAD & (NPAD-1)) == 0, "NPAD pow2");
    static_assert(!GATHER || MAPSZ >= IH*IW, "LDS map covers raster");
    __shared__ __align__(16) u16 sA[NPAD*KCp];
    __shared__ __align__(16) u16 sB[CO*KCp];
    __shared__ u16 smap[GATHER ? MAPSZ : 2];

    int b  = blockIdx.x / NB;
    int n0 = (blockIdx.x % NB)*NPAD;
    int tid = threadIdx.x;
    const u16* xb = in + (GATHER ? (size_t)b*INTOT*CI : (size_t)b*IH*IW*CI);

    if constexpr (GATHER){
        for (int i = tid; i < MAPSZ; i += BT) smap[i] = map[i];
    }
    if constexpr (KCm > KCd){
        constexpr int PADW = KCm - KCd;
        for (int e = tid; e < NPAD*PADW; e += BT)
            sA[(e/PADW)*KCp + KCd + e%PADW] = 0;
    }
    if constexpr (GATHER) __syncthreads();   // smap visible before stage A

    int w = tid >> 6, lane = tid & 63, l15 = lane & 15, l4 = lane >> 4;
    int wr = w / WC, wc = w % WC;
    f32x4 acc[WN][WM];
    #pragma unroll
    for (int i=0;i<WN;++i)
        #pragma unroll
        for (int j=0;j<WM;++j) acc[i][j] = (f32x4){0.f,0.f,0.f,0.f};

    for (int ch = 0; ch < NCH; ++ch){
        if (ch) __syncthreads();
        // stage A: per (n, tap, ch-vec8) one 16B copy; tap row is contiguous
        constexpr int ITER = NPAD*TPC*CIV;
        for (int i = tid; i < ITER; i += BT){
            int n_l = i / (TPC*CIV);
            int r   = i - n_l*(TPC*CIV);
            int tl  = r / CIV;
            int civ = r - tl*CIV;
            int n_g = min(n0 + n_l, NTOT-1);
            int oh = n_g/OW, ow = n_g - oh*OW;
            int tap = ch*TPC + tl;
            int u = tap/KW, v = tap - u*KW;
            int pos = (oh*S + u)*IW + ow*S + v;
            const u16* src;
            if constexpr (GATHER){
                int m = (int)smap[pos];              // LDS-resident u16 map
                src = xb + (size_t)m*CI + civ*8;
            } else {
                src = xb + (size_t)pos*CI + civ*8;
            }
            uint4 val = *reinterpret_cast<const uint4*>(src);
            *reinterpret_cast<uint4*>(&sA[n_l*KCp + tl*CI + civ*8]) = val;
        }
        // stage B: weights (16B copies)
        constexpr int W8 = KCm/8;
        for (int i = tid; i < CO*W8; i += BT){
            int co = i / W8, j = (i - co*W8)*8;
            uint4 v = *reinterpret_cast<const uint4*>(wh + ((size_t)co*NCH + ch)*KCm + j);
            *reinterpret_cast<uint4*>(&sB[co*KCp + j]) = v;
        }
        __syncthreads();
        // MFMA: wave (wr,wc) computes WN x WM tiles; (WN+WM) reads per step
        #pragma unroll
        for (int ks = 0; ks < KCm/32; ++ks){
            half8 a[WN], bf[WM];
            #pragma unroll
            for (int i=0;i<WN;++i)
                a[i] = *reinterpret_cast<const half8*>(
                    &sA[((wr*WN+i)*16 + l15)*KCp + ks*32 + l4*8]);
            #pragma unroll
            for (int j=0;j<WM;++j)
                bf[j] = *reinterpret_cast<const half8*>(
                    &sB[((wc*WM+j)*16 + l15)*KCp + ks*32 + l4*8]);
            #pragma unroll
            for (int i=0;i<WN;++i)
                #pragma unroll
                for (int j=0;j<WM;++j)
                    acc[i][j] = __builtin_amdgcn_mfma_f32_16x16x32_f16(a[i], bf[j], acc[i][j], 0, 0, 0);
        }
    }
    // epilogue: BN + lrelu, NHWC [b][n][co] (lanes -> consecutive co: coalesced)
    #pragma unroll
    for (int j=0;j<WM;++j){
        int co = (wc*WM+j)*16 + l15;
        float inv = bg[co]*rsqrtf(bv[co]+1e-5f);
        float shv = bb[co] - bm[co]*inv;
        #pragma unroll
        for (int i=0;i<WN;++i){
            #pragma unroll
            for (int r=0;r<4;++r){
                int gn = n0 + (wr*WN+i)*16 + l4*4 + r;
                if (gn < NTOT)
                    out[((size_t)b*NTOT + gn)*CO + co] = f2h(lrelu_f(fmaf(acc[i][j][r], inv, shv)));
            }
        }
    }
}

// ---------------------------------------------------------------------------
// Head GEMM: fused = lrelu(h5flat[256x2560] @ pwh^T + v@vproj^T + vproj_b).
// 64x64 tiles, grid(4,4). Output f16. (R15-verified.)
// ---------------------------------------------------------------------------
__global__ __launch_bounds__(256) void k_head2(
    const u16* __restrict__ h5, const u16* __restrict__ pwh,
    const float* __restrict__ vin, const float* __restrict__ vproj_w,
    const float* __restrict__ vproj_b, u16* __restrict__ fusedh)
{
    __shared__ __align__(16) u16 sA[64*136];
    __shared__ __align__(16) u16 sB[64*136];
    __shared__ float sv[64*9];
    int m0 = blockIdx.x*64, nc0 = blockIdx.y*64;
    int tid = threadIdx.x;
    int w = tid >> 6, lane = tid & 63, l15 = lane & 15, l4 = lane >> 4;
    f32x4 acc[4];
    #pragma unroll
    for (int j=0;j<4;++j) acc[j] = (f32x4){0.f,0.f,0.f,0.f};

    for (int i = tid; i < 576; i += 256) sv[i] = vin[(m0 + i/9)*9 + i%9];

    for (int kc0 = 0; kc0 < 2560; kc0 += 128){
        if (kc0) __syncthreads();
        for (int i = tid; i < 1024; i += 256){
            int r = i >> 4, jv = (i & 15)*8;
            *reinterpret_cast<uint4*>(&sA[r*136 + jv]) =
                *reinterpret_cast<const uint4*>(h5 + (size_t)(m0+r)*2560 + kc0 + jv);
            *reinterpret_cast<uint4*>(&sB[r*136 + jv]) =
                *reinterpret_cast<const uint4*>(pwh + (size_t)(nc0+r)*2560 + kc0 + jv);
        }
        __syncthreads();
        #pragma unroll
        for (int ks = 0; ks < 4; ++ks){
            half8 a = *reinterpret_cast<const half8*>(&sA[(w*16 + l15)*136 + ks*32 + l4*8]);
            #pragma unroll
            for (int j=0;j<4;++j){
                half8 bf = *reinterpret_cast<const half8*>(&sB[(j*16 + l15)*136 + ks*32 + l4*8]);
                acc[j] = __builtin_amdgcn_mfma_f32_16x16x32_f16(a, bf, acc[j], 0, 0, 0);
            }
        }
    }
    #pragma unroll
    for (int j=0;j<4;++j){
        int nc = nc0 + j*16 + l15;
        float bias = vproj_b[nc];
        #pragma unroll
        for (int r=0;r<4;++r){
            int ml = w*16 + l4*4 + r;
            float av = 0.f;
            #pragma unroll
            for (int k=0;k<9;++k) av = fmaf(sv[ml*9+k], vproj_w[nc*9+k], av);
            fusedh[(size_t)(m0+ml)*256 + nc] = f2h(lrelu_f(acc[j][r] + av + bias));
        }
    }
}

// ---------------------------------------------------------------------------
// GRU gate GEMM: gbuf[:,0:768] = fused @ wih^T ; gbuf[:,768:1536] = hx @ whh^T.
// grid(4, 24): y = half*12 + ntile. (R15-verified.)
// ---------------------------------------------------------------------------
__global__ __launch_bounds__(256) void k_ggemm(
    const u16* __restrict__ fusedh, const float* __restrict__ hx,
    const u16* __restrict__ wihh, const u16* __restrict__ whhh,
    float* __restrict__ gbuf)
{
    __shared__ __align__(16) u16 sA[64*136];
    __shared__ __align__(16) u16 sB[64*136];
    int m0 = blockIdx.x*64;
    int t  = blockIdx.y;
    int half = t / 12, nt = t - half*12;
    int n0 = nt*64;
    const u16* B = (half ? whhh : wihh) + (size_t)n0*256;
    int tid = threadIdx.x;
    int w = tid >> 6, lane = tid & 63, l15 = lane & 15, l4 = lane >> 4;
    f32x4 acc[4];
    #pragma unroll
    for (int j=0;j<4;++j) acc[j] = (f32x4){0.f,0.f,0.f,0.f};

    for (int kc0 = 0; kc0 < 256; kc0 += 128){
        if (kc0) __syncthreads();
        for (int i = tid; i < 1024; i += 256){
            int r = i >> 4, jv = (i & 15)*8;
            if (half == 0){
                *reinterpret_cast<uint4*>(&sA[r*136 + jv]) =
                    *reinterpret_cast<const uint4*>(fusedh + (size_t)(m0+r)*256 + kc0 + jv);
            } else {
                const float* src = hx + (size_t)(m0+r)*256 + kc0 + jv;
                float4 f0 = *reinterpret_cast<const float4*>(src);
                float4 f1 = *reinterpret_cast<const float4*>(src+4);
                u16 v[8] = { f2h(f0.x),f2h(f0.y),f2h(f0.z),f2h(f0.w),
                             f2h(f1.x),f2h(f1.y),f2h(f1.z),f2h(f1.w) };
                *reinterpret_cast<uint4*>(&sA[r*136 + jv]) = *reinterpret_cast<uint4*>(v);
            }
            *reinterpret_cast<uint4*>(&sB[r*136 + jv]) =
                *reinterpret_cast<const uint4*>(B + (size_t)r*256 + kc0 + jv);
        }
        __syncthreads();
        #pragma unroll
        for (int ks = 0; ks < 4; ++ks){
            half8 a = *reinterpret_cast<const half8*>(&sA[(w*16 + l15)*136 + ks*32 + l4*8]);
            #pragma unroll
            for (int j=0;j<4;++j){
                half8 bf = *reinterpret_cast<const half8*>(&sB[(j*16 + l15)*136 + ks*32 + l4*8]);
                acc[j] = __builtin_amdgcn_mfma_f32_16x16x32_f16(a, bf, acc[j], 0, 0, 0);
            }
        }
    }
    #pragma unroll
    for (int j=0;j<4;++j){
        int nc = half*768 + n0 + j*16 + l15;
        #pragma unroll
        for (int r=0;r<4;++r){
            int m = m0 + w*16 + l4*4 + r;
            gbuf[(size_t)m*1536 + nc] = acc[j][r];
        }
    }
}

// ---------------------------------------------------------------------------
// Fused GRU gate + act head (R17-verified).
// ---------------------------------------------------------------------------
__global__ __launch_bounds__(256) void k_gate_act(
    const float* __restrict__ gbuf, const float* __restrict__ hx,
    const float* __restrict__ bih, const float* __restrict__ bhh,
    const float* __restrict__ fc_w,
    float* __restrict__ hx_new, float* __restrict__ act)
{
    __shared__ float sh[256];
    int b = blockIdx.x, j = threadIdx.x;
    const float* g = gbuf + (size_t)b*1536;
    float ir = g[j]       + bih[j];
    float iz = g[256+j]   + bih[256+j];
    float in_= g[512+j]   + bih[512+j];
    float hr = g[768+j]   + bhh[j];
    float hz = g[1024+j]  + bhh[256+j];
    float hn = g[1280+j]  + bhh[512+j];
    float r = 1.f/(1.f+expf(-(ir+hr)));
    float z = 1.f/(1.f+expf(-(iz+hz)));
    float n = tanhf(in_ + r*hn);
    float h = (1.f-z)*n + z*hx[b*256+j];
    hx_new[b*256+j] = h;
    sh[j] = lrelu_f(h);
    __syncthreads();
    int w = j >> 6, lane = j & 63;
    const float* fw = fc_w + w*256;
    int k0 = lane*4;
    float a = sh[k0]*fw[k0] + sh[k0+1]*fw[k0+1] + sh[k0+2]*fw[k0+2] + sh[k0+3]*fw[k0+3];
    #pragma unroll
    for (int off = 32; off; off >>= 1) a += __shfl_down(a, off);
    if (lane == 0) act[b*4 + w] = a;
}

extern "C" void kernel_launch(void* const* d_in, const int* in_sizes, int n_in,
                              void* d_out, int out_size, void* d_ws, size_t ws_size,
                              hipStream_t stream)
{
    const float* x      = (const float*)d_in[0];
    const float* vin    = (const float*)d_in[1];
    const float* hx     = (const float*)d_in[2];
    const float* sc0_w  = (const float*)d_in[3];
    const float* bn0g   = (const float*)d_in[4];
    const float* bn0b   = (const float*)d_in[5];
    const float* bn0m   = (const float*)d_in[6];
    const float* bn0v   = (const float*)d_in[7];
    const float* sc1_w  = (const float*)d_in[8];
    const float* bn1g   = (const float*)d_in[9];
    const float* bn1b   = (const float*)d_in[10];
    const float* bn1m   = (const float*)d_in[11];
    const float* bn1v   = (const float*)d_in[12];
    const float* c2_w   = (const float*)d_in[13];
    const float* bn2g   = (const float*)d_in[14];
    const float* bn2b   = (const float*)d_in[15];
    const float* bn2m   = (const float*)d_in[16];
    const float* bn2v   = (const float*)d_in[17];
    const float* c3_w   = (const float*)d_in[18];
    const float* bn3g   = (const float*)d_in[19];
    const float* bn3b   = (const float*)d_in[20];
    const float* bn3m   = (const float*)d_in[21];
    const float* bn3v   = (const float*)d_in[22];
    const float* c4_w   = (const float*)d_in[23];
    const float* bn4g   = (const float*)d_in[24];
    const float* bn4b   = (const float*)d_in[25];
    const float* bn4m   = (const float*)d_in[26];
    const float* bn4v   = (const float*)d_in[27];
    const float* c5_w   = (const float*)d_in[28];
    const float* bn5g   = (const float*)d_in[29];
    const float* bn5b   = (const float*)d_in[30];
    const float* bn5m   = (const float*)d_in[31];
    const float* bn5v   = (const float*)d_in[32];
    const float* proj_w = (const float*)d_in[33];
    const float* vproj_w= (const float*)d_in[34];
    const float* vproj_b= (const float*)d_in[35];
    const float* gru_wih= (const float*)d_in[36];
    const float* gru_whh= (const float*)d_in[37];
    const float* gru_bih= (const float*)d_in[38];
    const float* gru_bhh= (const float*)d_in[39];
    const float* fc_w   = (const float*)d_in[40];

    char* base = (char*)d_ws;
    size_t off = 0;
    auto alloc = [&](size_t bytes)->char*{
        char* p = base + off; off += (bytes + 255) & ~(size_t)255; return p;
    };
    int* map0 = (int*)alloc((size_t)96*192*4);
    u16* map1h= (u16*)alloc((size_t)48*96*2);
    u16* wb0  = (u16*)alloc((size_t)32*2*128*2);
    u16* wb1  = (u16*)alloc((size_t)64*5*160*2);
    u16* wb2  = (u16*)alloc((size_t)64*3*192*2);
    u16* wb3  = (u16*)alloc((size_t)64*2*128*2);
    u16* wb4  = (u16*)alloc((size_t)128*3*192*2);
    u16* wb5  = (u16*)alloc((size_t)128*9*128*2);
    u16* pwh  = (u16*)alloc((size_t)256*2560*2);
    u16* wihh = (u16*)alloc((size_t)768*256*2);
    u16* whhh = (u16*)alloc((size_t)768*256*2);
    u16* xu   = (u16*)alloc((size_t)256*18432*8*2);   // xu0 only (xu1 folded)
    u16* h0   = (u16*)alloc((size_t)256*1953*32*2);
    u16* h1   = (u16*)alloc((size_t)256*465*64*2);
    u16* h2   = (u16*)alloc((size_t)256*377*64*2);
    u16* h3   = (u16*)alloc((size_t)256*84*64*2);
    u16* h4   = (u16*)alloc((size_t)256*48*128*2);
    u16* h5   = (u16*)alloc((size_t)256*20*128*2);
    u16* fusedh = (u16*)alloc((size_t)256*256*2);
    float* gbuf = (float*)alloc((size_t)256*1536*4);

    // ---- one-time prep (single launch, y-dispatched) ----
    PrepP pp = { map0, map1h, sc0_w, sc1_w, wb0, wb1,
                 c2_w, c3_w, c4_w, c5_w, wb2, wb3, wb4, wb5,
                 proj_w, gru_wih, gru_whh, pwh, wihh, whhh };
    k_prep<<<dim3(2560, 11), 256, 0, stream>>>(pp);

    // ---- backbone (NHWC, MFMA f16, 2-D wave tiles; big layers 8-wave) ----
    // k_nconv<BT,CO,OW,NTOT,NB,IH,IW,KW,S,CI,TPC,NCH,KCm,KCp,WR,WC,WN,WM[,GATHER,INTOT,MAPSZ]>
    k_xu0<<<dim3(72, 256), 256, 0, stream>>>(x, map0, xu);
    k_nconv<512,32,63,1953,8, 96,192, 5,3, 8,13,2, 128,136, 8,1,2,2>
        <<<256*8, 512, 0, stream>>>(xu, nullptr, wb0, bn0g,bn0b,bn0m,bn0v, h0);
    k_nconv<512,64,31,465,4, 48,96, 5,3, 32,5,5, 160,168, 4,2,2,2, 1,1953,4608>
        <<<256*4, 512, 0, stream>>>(h0, map1h, wb1, bn1g,bn1b,bn1m,bn1v, h1);
    k_nconv<512,64,29,377,3, 15,31, 3,1, 64,3,3, 192,200, 4,2,2,2>
        <<<256*3, 512, 0, stream>>>(h1, nullptr, wb2, bn2g,bn2b,bn2m,bn2v, h2);
    k_nconv<256,64,14,84,3, 13,29, 2,2, 64,2,2, 128,136, 2,2,1,2>
        <<<256*3, 256, 0, stream>>>(h2, nullptr, wb3, bn3g,bn3b,bn3m,bn3v, h3);
    k_nconv<256,128,12,48,3, 6,14, 3,1, 64,3,3, 192,200, 1,4,1,2>
        <<<256*3, 256, 0, stream>>>(h3, nullptr, wb4, bn4g,bn4b,bn4m,bn4v, h4);
    k_nconv<256,128,10,20,2, 4,12, 3,1, 128,1,9, 128,136, 1,4,1,2>
        <<<256*2, 256, 0, stream>>>(h4, nullptr, wb5, bn5g,bn5b,bn5m,bn5v, h5);

    // ---- head (MFMA GEMMs) ----
    k_head2<<<dim3(4,4), 256, 0, stream>>>(h5, pwh, vin, vproj_w, vproj_b, fusedh);
    k_ggemm<<<dim3(4,24), 256, 0, stream>>>(fusedh, hx, wihh, whhh, gbuf);
    float* outp = (float*)d_out;
    k_gate_act<<<256, 256, 0, stream>>>(gbuf, hx, gru_bih, gru_bhh, fc_w,
                                        outp + 1024, outp);
}